// Round 1
// baseline (60.287 us; speedup 1.0000x reference)
//
#include <hip/hip_runtime.h>
#include <hip/hip_bf16.h>
#include <stdint.h>

#define LOG2E 1.4426950408889634f

typedef __attribute__((ext_vector_type(4))) float f4;
typedef __attribute__((ext_vector_type(4))) int   i4;
typedef __attribute__((ext_vector_type(8))) short s8;   // 8 x bf16
typedef __attribute__((ext_vector_type(4))) short s4;   // 4 x bf16

#if defined(__has_builtin)
# if __has_builtin(__builtin_amdgcn_exp2f)
#  define EXP2F(x) __builtin_amdgcn_exp2f(x)
# else
#  define EXP2F(x) exp2f(x)
# endif
#else
# define EXP2F(x) exp2f(x)
#endif

static __device__ __forceinline__ uint32_t fbits(float f) {
  union { float f; uint32_t u; } c; c.f = f; return c.u;
}
static __device__ __forceinline__ uint16_t bf16_rne(float f) {
  uint32_t b = fbits(f);
  b += 0x7FFFu + ((b >> 16) & 1u);
  return (uint16_t)(b >> 16);
}
static __device__ __forceinline__ float bf2f(uint16_t u) {
  union { uint32_t u; float f; } c; c.u = ((uint32_t)u) << 16; return c.f;
}

// ---------------- K1: W (H,256,64) f32 -> WT (H,64,256) bf16 ----------------
__global__ __launch_bounds__(256) void k_prep_wt(const float* __restrict__ W,
                                                 uint16_t* __restrict__ WT) {
  int idx = (blockIdx.x * 256 + threadIdx.x) * 4;   // 65536 elems, grid 64
  f4 w = *(const f4*)(W + idx);
  int h = idx >> 14;
  int k = (idx >> 6) & 255;
  int o = idx & 63;
  uint16_t* base = WT + ((h << 6) + o) * 256 + k;
  base[0]   = bf16_rne(w.x);
  base[256] = bf16_rne(w.y);
  base[512] = bf16_rne(w.z);
  base[768] = bf16_rne(w.w);
}

// ------- K2: h = x @ W per head (MFMA), fused f1/f2 + hT bf16 store ---------
__global__ __launch_bounds__(256) void k_gemm_h(
    const float* __restrict__ x, const uint16_t* __restrict__ WT,
    const float* __restrict__ a,
    uint16_t* __restrict__ hT, float* __restrict__ f1, float* __restrict__ f2) {
  const int N = 4096, K = 256;
  __shared__ uint16_t xs[16][264];   // 16 rows x 256 k, +8 pad
  int t = threadIdx.x;
  int i0 = blockIdx.x * 16;
  {
    int r = t >> 4, c = (t & 15) << 4;
    const float* src = x + (i0 + r) * K + c;
    union { uint16_t u[16]; s8 v[2]; } tmp;
    #pragma unroll
    for (int i = 0; i < 16; i += 4) {
      f4 v = *(const f4*)(src + i);
      tmp.u[i+0] = bf16_rne(v.x); tmp.u[i+1] = bf16_rne(v.y);
      tmp.u[i+2] = bf16_rne(v.z); tmp.u[i+3] = bf16_rne(v.w);
    }
    *(s8*)&xs[r][c]     = tmp.v[0];
    *(s8*)&xs[r][c + 8] = tmp.v[1];
  }
  __syncthreads();
  int wave = t >> 6, lane = t & 63, lr = lane & 15, lc = lane >> 4;
  f4 acc[4];
  #pragma unroll
  for (int cg = 0; cg < 4; ++cg) acc[cg] = (f4){0.f, 0.f, 0.f, 0.f};
  #pragma unroll
  for (int ks = 0; ks < 8; ++ks) {
    s8 af = *(const s8*)&xs[lr][ks * 32 + lc * 8];
    #pragma unroll
    for (int cg = 0; cg < 4; ++cg) {
      s8 bf = *(const s8*)(WT + ((wave << 6) + (cg << 4) + lr) * 256 + ks * 32 + lc * 8);
      acc[cg] = __builtin_amdgcn_mfma_f32_16x16x32_bf16(af, bf, acc[cg], 0, 0, 0);
    }
  }
  // f1/f2 epilogue: f1[n] = sum_o h[n][o]*a1[o]
  float p1[4] = {0, 0, 0, 0}, p2[4] = {0, 0, 0, 0};
  #pragma unroll
  for (int cg = 0; cg < 4; ++cg) {
    float a1v = a[wave * 128 + (cg << 4) + lr];
    float a2v = a[wave * 128 + 64 + (cg << 4) + lr];
    #pragma unroll
    for (int q = 0; q < 4; ++q) {
      p1[q] = fmaf(acc[cg][q], a1v, p1[q]);
      p2[q] = fmaf(acc[cg][q], a2v, p2[q]);
    }
  }
  #pragma unroll
  for (int m = 1; m <= 8; m <<= 1) {
    #pragma unroll
    for (int q = 0; q < 4; ++q) {
      p1[q] += __shfl_xor(p1[q], m, 64);
      p2[q] += __shfl_xor(p2[q], m, 64);
    }
  }
  if (lr == 0) {
    #pragma unroll
    for (int q = 0; q < 4; ++q) {
      f1[wave * N + i0 + (lc << 2) + q] = p1[q];
      f2[wave * N + i0 + (lc << 2) + q] = p2[q];
    }
  }
  // hT[h][o][n] bf16
  #pragma unroll
  for (int cg = 0; cg < 4; ++cg) {
    union { uint16_t u[4]; s4 v; } h4;
    #pragma unroll
    for (int q = 0; q < 4; ++q) h4.u[q] = bf16_rne(acc[cg][q]);
    *(s4*)(hT + (size_t)((wave << 6) + (cg << 4) + lr) * N + i0 + (lc << 2)) = h4.v;
  }
}

// ---------------- K3: f2max per head ----------------
__global__ __launch_bounds__(256) void k_f2max(const float* __restrict__ f2,
                                               float* __restrict__ f2m) {
  __shared__ float red[256];
  int h = blockIdx.x, t = threadIdx.x;
  float m = -1e30f;
  for (int j = t; j < 4096; j += 256) m = fmaxf(m, f2[h * 4096 + j]);
  red[t] = m;
  __syncthreads();
  for (int s = 128; s > 0; s >>= 1) {
    if (t < s) red[t] = fmaxf(red[t], red[t + s]);
    __syncthreads();
  }
  if (t == 0) f2m[h] = red[0];
}

// -------- K4: flash partial: O_p = P_p @ h, l_p = rowsum(P_p) ----------
__global__ __launch_bounds__(256) void k_attn(
    const int* __restrict__ adj, const float* __restrict__ f1,
    const float* __restrict__ f2, const float* __restrict__ f2m,
    const uint16_t* __restrict__ hT,
    uint16_t* __restrict__ Op, float* __restrict__ lp, int NP) {
  const int N = 4096;
  __shared__ float adjf[64][68];   // +4 pad breaks bank aliasing
  int p = blockIdx.x % NP, rb = blockIdx.x / NP;
  int i0 = rb << 6;
  int jcount = N / NP, jbase = p * jcount, ntiles = jcount >> 6;
  int t = threadIdx.x, wave = t >> 6, lane = t & 63, lr = lane & 15, lc = lane >> 4;

  float fm = f2m[wave];
  float d1[4], d2[4], lsum[4] = {0, 0, 0, 0};
  #pragma unroll
  for (int g = 0; g < 4; ++g) {
    float f1v = f1[wave * N + i0 + (g << 4) + lr];
    float s = f1v + fm;
    float M = fmaxf(s, 0.2f * s);               // static per-row upper bound
    d1[g] = fmaf(f1v, LOG2E, -M * LOG2E);
    d2[g] = fmaf(f1v, 0.2f * LOG2E, -M * LOG2E);
  }
  f4 acc[4][4];
  #pragma unroll
  for (int g = 0; g < 4; ++g)
    #pragma unroll
    for (int cg = 0; cg < 4; ++cg) acc[g][cg] = (f4){0.f, 0.f, 0.f, 0.f};

  int str = t >> 2, stc = (t & 3) << 4;
  const int* asrc = adj + (size_t)(i0 + str) * N + jbase + stc;
  const uint16_t* hTb = hT + (size_t)((wave << 6) + lr) * N + jbase + (lc << 3);
  const float* f2b = f2 + wave * N + jbase + (lc << 3);

  i4 av[4];
  #pragma unroll
  for (int i = 0; i < 4; ++i) av[i] = *(const i4*)(asrc + 4 * i);
  asrc += 64;

  for (int tile = 0; tile < ntiles; ++tile) {
    {
      float* dst = &adjf[str][stc];
      #pragma unroll
      for (int i = 0; i < 4; ++i) {
        f4 fv;
        fv.x = (float)av[i].x; fv.y = (float)av[i].y;
        fv.z = (float)av[i].z; fv.w = (float)av[i].w;
        *(f4*)(dst + 4 * i) = fv;
      }
    }
    __syncthreads();
    if (tile + 1 < ntiles) {   // prefetch next adj tile under compute
      #pragma unroll
      for (int i = 0; i < 4; ++i) av[i] = *(const i4*)(asrc + 4 * i);
      asrc += 64;
    }
    #pragma unroll
    for (int ks = 0; ks < 2; ++ks) {
      f4 f2v0 = *(const f4*)(f2b + tile * 64 + ks * 32);
      f4 f2v1 = *(const f4*)(f2b + tile * 64 + ks * 32 + 4);
      s8 bf[4];
      #pragma unroll
      for (int cg = 0; cg < 4; ++cg)
        bf[cg] = *(const s8*)(hTb + (size_t)(cg << 4) * N + tile * 64 + (ks << 5));
      #pragma unroll
      for (int g = 0; g < 4; ++g) {
        const float* arow = &adjf[(g << 4) + lr][(ks << 5) + (lc << 3)];
        f4 ar0 = *(const f4*)arow;
        f4 ar1 = *(const f4*)(arow + 4);
        float pe[8];
        #pragma unroll
        for (int e = 0; e < 8; ++e) {
          float f2e = (e < 4) ? f2v0[e] : f2v1[e - 4];
          float ae  = (e < 4) ? ar0[e]  : ar1[e - 4];
          float arg = fmaxf(fmaf(f2e, LOG2E, d1[g]),
                            fmaf(f2e, 0.2f * LOG2E, d2[g]));
          float pv = EXP2F(arg) * ae;    // mask: multiply by 0/1
          lsum[g] += pv;
          pe[e] = pv;
        }
        union { uint32_t u[4]; s8 v; } af;
        #pragma unroll
        for (int i = 0; i < 4; ++i)
          af.u[i] = __builtin_amdgcn_perm(fbits(pe[2 * i + 1]) + 0x8000u,
                                          fbits(pe[2 * i]) + 0x8000u,
                                          0x07060302u);
        #pragma unroll
        for (int cg = 0; cg < 4; ++cg)
          acc[g][cg] = __builtin_amdgcn_mfma_f32_16x16x32_bf16(af.v, bf[cg],
                                                               acc[g][cg], 0, 0, 0);
      }
    }
    __syncthreads();
  }
  // store partials
  uint16_t* ob = Op + (size_t)((p << 2) + wave) * N * 64 + (size_t)i0 * 64;
  #pragma unroll
  for (int g = 0; g < 4; ++g) {
    #pragma unroll
    for (int cg = 0; cg < 4; ++cg) {
      #pragma unroll
      for (int q = 0; q < 4; ++q)
        ob[((g << 4) + (lc << 2) + q) * 64 + (cg << 4) + lr] = bf16_rne(acc[g][cg][q]);
    }
    float v = lsum[g];
    v += __shfl_xor(v, 16, 64);
    v += __shfl_xor(v, 32, 64);
    if (lane < 16) lp[(size_t)((p << 2) + wave) * N + i0 + (g << 4) + lane] = v;
  }
}

// ---------------- K5: out = sum_p O_p / sum_p l_p ----------------
__global__ __launch_bounds__(256) void k_combine(
    const uint16_t* __restrict__ Op, const float* __restrict__ lp,
    float* __restrict__ out, int NP) {
  int idx = blockIdx.x * 256 + threadIdx.x;   // 262144 threads, 4 f32 each
  int n = idx >> 6;
  int c4 = (idx & 63) << 2;
  int h = c4 >> 6, o = c4 & 63;
  float s0 = 0, s1 = 0, s2 = 0, s3 = 0, ls = 0;
  for (int p = 0; p < NP; ++p) {
    size_t base = (size_t)((p << 2) + h) * 4096 + n;
    s4 v = *(const s4*)(Op + base * 64 + o);
    s0 += bf2f((uint16_t)v[0]); s1 += bf2f((uint16_t)v[1]);
    s2 += bf2f((uint16_t)v[2]); s3 += bf2f((uint16_t)v[3]);
    ls += lp[base];
  }
  float inv = (ls > 0.f) ? 1.0f / ls : 0.f;
  f4 r = {s0 * inv, s1 * inv, s2 * inv, s3 * inv};
  *(f4*)(out + (size_t)n * 256 + c4) = r;
}

extern "C" void kernel_launch(void* const* d_in, const int* in_sizes, int n_in,
                              void* d_out, int out_size, void* d_ws, size_t ws_size,
                              hipStream_t stream) {
  (void)in_sizes; (void)n_in; (void)out_size;
  const float* x   = (const float*)d_in[0];
  const int*   adj = (const int*)d_in[1];
  const float* W   = (const float*)d_in[2];
  const float* a   = (const float*)d_in[3];
  float* out = (float*)d_out;
  char* ws = (char*)d_ws;

  size_t oWT = 0;
  size_t oHT = oWT + 131072;      // WT: 4*64*256*2
  size_t oF1 = oHT + 2097152;     // hT: 4*64*4096*2
  size_t oF2 = oF1 + 65536;       // f1: 4*4096*4
  size_t oFM = oF2 + 65536;       // f2
  size_t oOP = (oFM + 16 + 255) & ~(size_t)255;

  int NP = 8;
  while (NP > 1 && oOP + (size_t)NP * (2097152 + 65536) > ws_size) NP >>= 1;
  size_t oLP = oOP + (size_t)NP * 2097152;

  uint16_t* WT  = (uint16_t*)(ws + oWT);
  uint16_t* hT  = (uint16_t*)(ws + oHT);
  float*    f1  = (float*)(ws + oF1);
  float*    f2  = (float*)(ws + oF2);
  float*    f2m = (float*)(ws + oFM);
  uint16_t* Op  = (uint16_t*)(ws + oOP);
  float*    lp  = (float*)(ws + oLP);

  k_prep_wt<<<64, 256, 0, stream>>>(W, WT);
  k_gemm_h<<<256, 256, 0, stream>>>(x, WT, a, hT, f1, f2);
  k_f2max<<<4, 256, 0, stream>>>(f2, f2m);
  k_attn<<<64 * NP, 256, 0, stream>>>(adj, f1, f2, f2m, hT, Op, lp, NP);
  k_combine<<<1024, 256, 0, stream>>>(Op, lp, out, NP);
}